// Round 20
// baseline (275.060 us; speedup 1.0000x reference)
//
#include <hip/hip_runtime.h>

#define BB 4
#define NN 10000
#define EE 160000
#define HID 256
#define NHEAD 8

typedef __attribute__((ext_vector_type(8))) short short8v;
typedef __attribute__((ext_vector_type(4))) float f32x4;

__device__ __forceinline__ unsigned short f2bf(float f) {
  unsigned u = __float_as_uint(f);
  unsigned r = (u + 0x7fffu + ((u >> 16) & 1u)) >> 16;
  return (unsigned short)r;
}
__device__ __forceinline__ float bf2f(unsigned short u) {
  return __uint_as_float(((unsigned)u) << 16);
}

// ---- prep: blocks 0-31 pack Bpack; block 32: What + We16; blocks 33-72:
// zero cnt/cur.
__global__ __launch_bounds__(512) void k_prep(
    const float* __restrict__ We, const float* __restrict__ ae,
    const float* __restrict__ Wn, const float* __restrict__ Wr,
    float* __restrict__ What, unsigned short* __restrict__ We16,
    unsigned short* __restrict__ Bpack, int* __restrict__ cnt,
    int* __restrict__ cur) {
  const int t = threadIdx.x;
  if (blockIdx.x >= 33) {
    const int zb = blockIdx.x - 33;  // 0..39
    int* __restrict__ dst = (zb < 20) ? cnt : cur;
    const int idx = (zb % 20) * 512 + t;
    if (idx < NN) dst[idx] = 0;
    return;
  }
  if (blockIdx.x == 32) {
    int k = t >> 3, hh = t & 7;
    float s = 0.f;
#pragma unroll
    for (int d = 0; d < 32; ++d) s += We[k * HID + hh * 32 + d] * ae[hh * 32 + d];
    What[k * NHEAD + hh] = s;
    for (int j = t; j < 64 * HID; j += 512) We16[j] = f2bf(We[j]);
    return;
  }
  if (t >= 256) return;
  const int nt = blockIdx.x;           // 0..31
  const int ks = t >> 6;               // 0..3
  const int l = t & 63;
  const int k0 = ks * 32 + (l >> 4) * 8;
  const float* __restrict__ src = (nt < 16) ? Wn : Wr;
  const int c2 = (nt * 16 + (l & 15)) & 255;
  short8v v;
#pragma unroll
  for (int e = 0; e < 8; ++e) v[e] = f2bf(src[(k0 + e) * HID + c2]);
  *reinterpret_cast<short8v*>(Bpack + ((size_t)(nt * 4 + ks) * 64 + l) * 8) = v;
}

// ---- MFMA projection (blocks 0-624) + edge histogram (blocks 625+).
__global__ __launch_bounds__(512) void k_projm(
    const float* __restrict__ nf, const unsigned short* __restrict__ Bpack,
    const float* __restrict__ as_, const float* __restrict__ ad_,
    unsigned short* __restrict__ h16, float* __restrict__ out,
    float* __restrict__ ssrc, float* __restrict__ sdst,
    const int* __restrict__ ei, int* __restrict__ cnt) {
  const int t = threadIdx.x;
  if (blockIdx.x >= 625) {  // fused k_hist
    const int e = (blockIdx.x - 625) * 512 + t;
    if (e < EE) atomicAdd(&cnt[ei[EE + e]], 1);
    return;
  }
  const int w = t >> 6, l = t & 63;
  const int base = blockIdx.x * 64 + (w & 3) * 16;
  const int nhalf = w >> 2;
  const int arow = base + (l & 15);
  short8v a[4];
#pragma unroll
  for (int ks = 0; ks < 4; ++ks) {
    const float* p = nf + (size_t)arow * 128 + ks * 32 + (l >> 4) * 8;
    const float4 f0 = *reinterpret_cast<const float4*>(p);
    const float4 f1 = *reinterpret_cast<const float4*>(p + 4);
    short8v v;
    v[0] = f2bf(f0.x); v[1] = f2bf(f0.y); v[2] = f2bf(f0.z); v[3] = f2bf(f0.w);
    v[4] = f2bf(f1.x); v[5] = f2bf(f1.y); v[6] = f2bf(f1.z); v[7] = f2bf(f1.w);
    a[ks] = v;
  }
  f32x4 acc[16];
#pragma unroll
  for (int i = 0; i < 16; ++i) acc[i] = (f32x4){0.f, 0.f, 0.f, 0.f};
  const short8v* bp =
      reinterpret_cast<const short8v*>(Bpack) + (size_t)nhalf * 4096 + l;
#pragma unroll
  for (int nt = 0; nt < 16; ++nt) {
#pragma unroll
    for (int ks = 0; ks < 4; ++ks) {
      const short8v bf = bp[(nt * 4 + ks) * 64];
      acc[nt] = __builtin_amdgcn_mfma_f32_16x16x32_bf16(a[ks], bf, acc[nt], 0, 0, 0);
    }
  }
  unsigned short* __restrict__ resOv = reinterpret_cast<unsigned short*>(out);
#pragma unroll
  for (int b = 0; b < 4; ++b) {
    const int bn = base + (l >> 4) * 4 + b;
    if (nhalf == 0) {
      const int bb = bn / NN, n = bn - bb * NN;
      unsigned short* __restrict__ rowp = h16 + (((size_t)n * 4 + bb) << 8);
#pragma unroll
      for (int nt = 0; nt < 16; ++nt) rowp[nt * 16 + (l & 15)] = f2bf(acc[nt][b]);
    } else {
      unsigned short* __restrict__ rowp = resOv + ((size_t)bn << 9);
#pragma unroll
      for (int nt = 0; nt < 16; ++nt) rowp[nt * 16 + (l & 15)] = f2bf(acc[nt][b]);
    }
  }
  // fused attention scalars (waves 0-3 only)
  if (nhalf == 0) {
    const int lo = l & 15;
#pragma unroll
    for (int h = 0; h < 8; ++h) {
      const float a0 = as_[h * 32 + lo], a1 = as_[h * 32 + 16 + lo];
      const float d0 = ad_[h * 32 + lo], d1 = ad_[h * 32 + 16 + lo];
#pragma unroll
      for (int rb = 0; rb < 4; ++rb) {
        float ps = acc[2 * h][rb] * a0 + acc[2 * h + 1][rb] * a1;
        float pd = acc[2 * h][rb] * d0 + acc[2 * h + 1][rb] * d1;
#pragma unroll
        for (int off = 1; off <= 8; off <<= 1) {
          ps += __shfl_xor(ps, off);
          pd += __shfl_xor(pd, off);
        }
        if (lo == 0) {
          const int bn = base + (l >> 4) * 4 + rb;
          ssrc[(size_t)bn * NHEAD + h] = ps;
          sdst[(size_t)bn * NHEAD + h] = pd;
        }
      }
    }
  }
}

__global__ __launch_bounds__(1024) void k_scan(const int* __restrict__ cnt,
                                               int* __restrict__ off) {
  __shared__ int ls[1024];
  const int t = threadIdx.x;
  int own = 0;
  int deg[10];
  if (t < 1000) {
#pragma unroll
    for (int i = 0; i < 10; ++i) { deg[i] = cnt[t * 10 + i]; own += deg[i]; }
  }
  ls[t] = own;
  __syncthreads();
  for (int s = 1; s < 1024; s <<= 1) {
    int v = 0;
    if (t >= s) v = ls[t - s];
    __syncthreads();
    if (t >= s) ls[t] += v;
    __syncthreads();
  }
  if (t < 1000) {
    int start = ls[t] - own;
#pragma unroll
    for (int i = 0; i < 10; ++i) { off[t * 10 + i] = start; start += deg[i]; }
  }
  if (t == 0) off[NN] = EE;
}

__global__ void k_scatter(const int* __restrict__ ei, const int* __restrict__ off,
                          int* __restrict__ cur, int2* __restrict__ eidx,
                          int* __restrict__ inv) {
  int e = blockIdx.x * 256 + threadIdx.x;
  if (e >= EE) return;
  int s = ei[e], d = ei[EE + e];
  int pos = off[d] + atomicAdd(&cur[d], 1);
  eidx[pos] = make_int2(e, s);
  inv[e] = pos;
}

// ---- edge logits -> exp(logit) directly, CSR-order [pos][b][8].
__global__ __launch_bounds__(256) void k_elogit(
    const float* __restrict__ ea, const int* __restrict__ ei,
    const float* __restrict__ What, const float* __restrict__ ssrc,
    const float* __restrict__ sdst, const int* __restrict__ inv,
    float* __restrict__ exP) {
  __shared__ float sea[32 * 65];
  __shared__ float sw[64 * NHEAD];
  const int t = threadIdx.x;
  sw[t] = What[t];
  sw[t + 256] = What[t + 256];
  const int g0 = blockIdx.x * 32;
  const float* base = ea + (size_t)g0 * 64;
#pragma unroll
  for (int j = 0; j < 8; ++j) {
    int f = t + j * 256;
    sea[(f >> 6) * 65 + (f & 63)] = base[f];
  }
  __syncthreads();
  const int il = t >> 3, hh = t & 7;
  const int g = g0 + il;
  float acc = 0.f;
#pragma unroll
  for (int k = 0; k < 64; ++k) acc += sea[il * 65 + k] * sw[k * NHEAD + hh];
  const int b = g / EE, e = g - b * EE;
  const int src = ei[e], dst = ei[EE + e];
  float lg = ssrc[((size_t)b * NN + src) * NHEAD + hh] +
             sdst[((size_t)b * NN + dst) * NHEAD + hh] + acc;
  lg = lg > 0.f ? lg : 0.2f * lg;
  const int pos = inv[e];
  exP[(((size_t)pos * 4 + b) << 3) + hh] = __expf(lg);
}

// ---- aggregation: ONE node per block, 4-WIDE chain within the node.
// wave = batch; block = node. Each main-loop iteration issues the gathers of
// FOUR edges (independent chains, 16 VMEMs back-to-back) then consumes them:
// exposed gather latency drops to ~1 per 4 edges with only ONE node's
// accumulator state (13 floats) -- quad-node's MLP at dual's register cost.
struct EData {
  float4 xa, xb;
  float exu, ssv, eal;
  ushort4 h4;
};

#define LOADD(i, es, d)                                                        \
  {                                                                            \
    const float* exi = exb + ((size_t)(i) << 5);                               \
    d.xa = *reinterpret_cast<const float4*>(exi);                              \
    d.xb = *reinterpret_cast<const float4*>(exi + 4);                          \
    d.exu = exi[hq];                                                           \
    d.ssv = exi[hr];                                                           \
    d.eal = eab[(size_t)(es).x * 64 + l];                                      \
    d.h4 = *reinterpret_cast<const ushort4*>(hb + ((size_t)(es).y << 10) + 4 * l); \
  }

#define COMP(d)                                                                \
  {                                                                            \
    z0 += d.xa.x * d.eal; z1 += d.xa.y * d.eal;                                \
    z2 += d.xa.z * d.eal; z3 += d.xa.w * d.eal;                                \
    z4 += d.xb.x * d.eal; z5 += d.xb.y * d.eal;                                \
    z6 += d.xb.z * d.eal; z7 += d.xb.w * d.eal;                                \
    ss += d.ssv;                                                               \
    u4.x += d.exu * bf2f(d.h4.x); u4.y += d.exu * bf2f(d.h4.y);                \
    u4.z += d.exu * bf2f(d.h4.z); u4.w += d.exu * bf2f(d.h4.w);                \
  }

__global__ __launch_bounds__(256, 4) void k_agg(
    const float* __restrict__ ea, const unsigned short* __restrict__ h16,
    const float* __restrict__ exP, const int* __restrict__ off,
    const int2* __restrict__ eidx, const unsigned short* __restrict__ We16,
    const float* __restrict__ gam, const float* __restrict__ bet,
    float* __restrict__ out) {
  __shared__ float zsh[4][8 * 65];
  const int wid = threadIdx.x >> 6, l = threadIdx.x & 63;
  const int b = wid, node = blockIdx.x;
  const int start = off[node], end = off[node + 1];
  const int hq = l >> 3;   // head owning this lane's 4 u-channels
  const int hr = l & 7;    // head this lane sums for ssum
  float4 u4 = {0.f, 0.f, 0.f, 0.f};
  float z0 = 0.f, z1 = 0.f, z2 = 0.f, z3 = 0.f;
  float z4 = 0.f, z5 = 0.f, z6 = 0.f, z7 = 0.f;
  float ss = 0.f;
  const float* __restrict__ exb = exP + ((size_t)b << 3);
  const float* __restrict__ eab = ea + (size_t)b * EE * 64;
  const unsigned short* __restrict__ hb = h16 + ((size_t)b << 8);
  int j = start;
  const int n4 = start + ((end - start) & ~3);
  // 4-wide main loop: 4 independent gather chains issued before any use
  for (; j < n4; j += 4) {
    const int2 e0 = eidx[j], e1 = eidx[j + 1];
    const int2 e2 = eidx[j + 2], e3 = eidx[j + 3];
    EData d0, d1, d2, d3;
    LOADD(j, e0, d0);
    LOADD(j + 1, e1, d1);
    LOADD(j + 2, e2, d2);
    LOADD(j + 3, e3, d3);
    COMP(d0);
    COMP(d1);
    COMP(d2);
    COMP(d3);
  }
  // tail (<=3 edges)
  for (; j < end; ++j) {
    const int2 es = eidx[j];
    EData d;
    LOADD(j, es, d);
    COMP(d);
  }
  // epilogue: z@We16 + residual(overlay) + normalize + LN + ELU (R9 form)
  zsh[wid][0 * 65 + l] = z0; zsh[wid][1 * 65 + l] = z1;
  zsh[wid][2 * 65 + l] = z2; zsh[wid][3 * 65 + l] = z3;
  zsh[wid][4 * 65 + l] = z4; zsh[wid][5 * 65 + l] = z5;
  zsh[wid][6 * 65 + l] = z6; zsh[wid][7 * 65 + l] = z7;
  const size_t bn = (size_t)b * NN + node;
  const ushort4 r16 = *reinterpret_cast<const ushort4*>(
      reinterpret_cast<const unsigned short*>(out) + (bn << 9) + 4 * l);
#pragma unroll 8
  for (int k = 0; k < 64; ++k) {
    const float zk = zsh[wid][hq * 65 + k];
    const ushort4 wv = *reinterpret_cast<const ushort4*>(We16 + (k << 8) + 4 * l);
    u4.x += zk * bf2f(wv.x); u4.y += zk * bf2f(wv.y);
    u4.z += zk * bf2f(wv.z); u4.w += zk * bf2f(wv.w);
  }
  const float ssq = __shfl(ss, hq);  // lane #hq (hr==hq) holds head hq's sum
  const float sc = ssq > 0.f ? 1.f / ssq : 0.f;
  u4.x = u4.x * sc + bf2f(r16.x); u4.y = u4.y * sc + bf2f(r16.y);
  u4.z = u4.z * sc + bf2f(r16.z); u4.w = u4.w * sc + bf2f(r16.w);
  // fused LayerNorm + ELU (wave holds the full 256-channel row)
  float s1 = u4.x + u4.y + u4.z + u4.w;
  float s2 = u4.x * u4.x + u4.y * u4.y + u4.z * u4.z + u4.w * u4.w;
#pragma unroll
  for (int off2 = 1; off2 <= 32; off2 <<= 1) {
    s1 += __shfl_xor(s1, off2);
    s2 += __shfl_xor(s2, off2);
  }
  const float mu = s1 * (1.f / HID);
  const float var = s2 * (1.f / HID) - mu * mu;
  const float rstd = rsqrtf(var + 1e-5f);
  const float4 g4 = reinterpret_cast<const float4*>(gam)[l];
  const float4 b4 = reinterpret_cast<const float4*>(bet)[l];
  float4 y;
  y.x = (u4.x - mu) * rstd * g4.x + b4.x;
  y.y = (u4.y - mu) * rstd * g4.y + b4.y;
  y.z = (u4.z - mu) * rstd * g4.z + b4.z;
  y.w = (u4.w - mu) * rstd * g4.w + b4.w;
  y.x = y.x > 0.f ? y.x : expm1f(y.x);
  y.y = y.y > 0.f ? y.y : expm1f(y.y);
  y.z = y.z > 0.f ? y.z : expm1f(y.z);
  y.w = y.w > 0.f ? y.w : expm1f(y.w);
  *reinterpret_cast<float4*>(out + (bn << 8) + 4 * l) = y;
}

extern "C" void kernel_launch(void* const* d_in, const int* in_sizes, int n_in,
                              void* d_out, int out_size, void* d_ws, size_t ws_size,
                              hipStream_t stream) {
  const float* nf   = (const float*)d_in[0];
  const int*   ei   = (const int*)d_in[1];
  const float* eatt = (const float*)d_in[2];
  const float* Wn   = (const float*)d_in[3];
  const float* We   = (const float*)d_in[4];
  const float* Wr   = (const float*)d_in[5];
  const float* as_  = (const float*)d_in[6];
  const float* ad_  = (const float*)d_in[7];
  const float* ae_  = (const float*)d_in[8];
  const float* gam  = (const float*)d_in[9];
  const float* bet  = (const float*)d_in[10];
  float* out = (float*)d_out;

  // ---- workspace layout (~50 MB)
  char* ws = (char*)d_ws;
  size_t o = 0;
  auto alloc = [&](size_t bytes) -> void* {
    void* p = ws + o;
    o += (bytes + 255) & ~(size_t)255;
    return p;
  };
  unsigned short* h16  = (unsigned short*)alloc((size_t)BB * NN * HID * 2);
  float* ssrc   = (float*)alloc((size_t)BB * NN * NHEAD * 4);
  float* sdst   = (float*)alloc((size_t)BB * NN * NHEAD * 4);
  float* What   = (float*)alloc(64 * NHEAD * 4);
  unsigned short* We16 = (unsigned short*)alloc(64 * HID * 2);
  float* exP    = (float*)alloc((size_t)BB * EE * NHEAD * 4);
  int*  cnt     = (int*)alloc(NN * 4);
  int*  cur     = (int*)alloc(NN * 4);
  int*  offn    = (int*)alloc((NN + 1) * 4);
  int2* eidx    = (int2*)alloc((size_t)(EE + 4) * 8);
  int*  inv     = (int*)alloc((size_t)EE * 4);
  unsigned short* Bpack = (unsigned short*)alloc((size_t)512 * 128 * 2);

  hipLaunchKernelGGL(k_prep, dim3(73), dim3(512), 0, stream,
                     We, ae_, Wn, Wr, What, We16, Bpack, cnt, cur);
  hipLaunchKernelGGL(k_projm, dim3(625 + (EE + 511) / 512), dim3(512), 0, stream,
                     nf, Bpack, as_, ad_, h16, out, ssrc, sdst, ei, cnt);
  hipLaunchKernelGGL(k_scan, dim3(1), dim3(1024), 0, stream, cnt, offn);
  hipLaunchKernelGGL(k_scatter, dim3((EE + 255) / 256), dim3(256), 0, stream,
                     ei, offn, cur, eidx, inv);
  hipLaunchKernelGGL(k_elogit, dim3(BB * EE / 32), dim3(256), 0, stream,
                     eatt, ei, What, ssrc, sdst, inv, exP);
  hipLaunchKernelGGL(k_agg, dim3(NN), dim3(256), 0, stream,
                     eatt, h16, exP, offn, eidx, We16, gam, bet, out);
}

// Round 21
// 241.810 us; speedup vs baseline: 1.1375x; 1.1375x over previous
//
#include <hip/hip_runtime.h>

#define BB 4
#define NN 10000
#define EE 160000
#define HID 256
#define NHEAD 8

typedef __attribute__((ext_vector_type(8))) short short8v;
typedef __attribute__((ext_vector_type(4))) float f32x4;

__device__ __forceinline__ unsigned short f2bf(float f) {
  unsigned u = __float_as_uint(f);
  unsigned r = (u + 0x7fffu + ((u >> 16) & 1u)) >> 16;
  return (unsigned short)r;
}
__device__ __forceinline__ float bf2f(unsigned short u) {
  return __uint_as_float(((unsigned)u) << 16);
}

// ---- prep: blocks 0-31 pack Bpack; block 32: What + We16; blocks 33-72:
// zero cnt/cur (replaces the separate hipMemsetAsync dispatch).
__global__ __launch_bounds__(512) void k_prep(
    const float* __restrict__ We, const float* __restrict__ ae,
    const float* __restrict__ Wn, const float* __restrict__ Wr,
    float* __restrict__ What, unsigned short* __restrict__ We16,
    unsigned short* __restrict__ Bpack, int* __restrict__ cnt,
    int* __restrict__ cur) {
  const int t = threadIdx.x;
  if (blockIdx.x >= 33) {
    const int zb = blockIdx.x - 33;  // 0..39
    int* __restrict__ dst = (zb < 20) ? cnt : cur;
    const int idx = (zb % 20) * 512 + t;
    if (idx < NN) dst[idx] = 0;
    return;
  }
  if (blockIdx.x == 32) {
    int k = t >> 3, hh = t & 7;
    float s = 0.f;
#pragma unroll
    for (int d = 0; d < 32; ++d) s += We[k * HID + hh * 32 + d] * ae[hh * 32 + d];
    What[k * NHEAD + hh] = s;
    for (int j = t; j < 64 * HID; j += 512) We16[j] = f2bf(We[j]);
    return;
  }
  if (t >= 256) return;
  const int nt = blockIdx.x;           // 0..31
  const int ks = t >> 6;               // 0..3
  const int l = t & 63;
  const int k0 = ks * 32 + (l >> 4) * 8;
  const float* __restrict__ src = (nt < 16) ? Wn : Wr;
  const int c2 = (nt * 16 + (l & 15)) & 255;
  short8v v;
#pragma unroll
  for (int e = 0; e < 8; ++e) v[e] = f2bf(src[(k0 + e) * HID + c2]);
  *reinterpret_cast<short8v*>(Bpack + ((size_t)(nt * 4 + ks) * 64 + l) * 8) = v;
}

// ---- MFMA projection (blocks 0-624) + edge histogram (blocks 625+).
// waves 0-3 -> h16 ([n][b][256] bf16) + fused attention scalars;
// waves 4-7 -> res overlay in d_out (first 512B of each (b,n) 1KB slot).
__global__ __launch_bounds__(512) void k_projm(
    const float* __restrict__ nf, const unsigned short* __restrict__ Bpack,
    const float* __restrict__ as_, const float* __restrict__ ad_,
    unsigned short* __restrict__ h16, float* __restrict__ out,
    float* __restrict__ ssrc, float* __restrict__ sdst,
    const int* __restrict__ ei, int* __restrict__ cnt) {
  const int t = threadIdx.x;
  if (blockIdx.x >= 625) {  // fused k_hist
    const int e = (blockIdx.x - 625) * 512 + t;
    if (e < EE) atomicAdd(&cnt[ei[EE + e]], 1);
    return;
  }
  const int w = t >> 6, l = t & 63;
  const int base = blockIdx.x * 64 + (w & 3) * 16;
  const int nhalf = w >> 2;
  const int arow = base + (l & 15);
  short8v a[4];
#pragma unroll
  for (int ks = 0; ks < 4; ++ks) {
    const float* p = nf + (size_t)arow * 128 + ks * 32 + (l >> 4) * 8;
    const float4 f0 = *reinterpret_cast<const float4*>(p);
    const float4 f1 = *reinterpret_cast<const float4*>(p + 4);
    short8v v;
    v[0] = f2bf(f0.x); v[1] = f2bf(f0.y); v[2] = f2bf(f0.z); v[3] = f2bf(f0.w);
    v[4] = f2bf(f1.x); v[5] = f2bf(f1.y); v[6] = f2bf(f1.z); v[7] = f2bf(f1.w);
    a[ks] = v;
  }
  f32x4 acc[16];
#pragma unroll
  for (int i = 0; i < 16; ++i) acc[i] = (f32x4){0.f, 0.f, 0.f, 0.f};
  const short8v* bp =
      reinterpret_cast<const short8v*>(Bpack) + (size_t)nhalf * 4096 + l;
#pragma unroll
  for (int nt = 0; nt < 16; ++nt) {
#pragma unroll
    for (int ks = 0; ks < 4; ++ks) {
      const short8v bf = bp[(nt * 4 + ks) * 64];
      acc[nt] = __builtin_amdgcn_mfma_f32_16x16x32_bf16(a[ks], bf, acc[nt], 0, 0, 0);
    }
  }
  unsigned short* __restrict__ resOv = reinterpret_cast<unsigned short*>(out);
#pragma unroll
  for (int b = 0; b < 4; ++b) {
    const int bn = base + (l >> 4) * 4 + b;
    if (nhalf == 0) {
      const int bb = bn / NN, n = bn - bb * NN;
      unsigned short* __restrict__ rowp = h16 + (((size_t)n * 4 + bb) << 8);
#pragma unroll
      for (int nt = 0; nt < 16; ++nt) rowp[nt * 16 + (l & 15)] = f2bf(acc[nt][b]);
    } else {
      unsigned short* __restrict__ rowp = resOv + ((size_t)bn << 9);
#pragma unroll
      for (int nt = 0; nt < 16; ++nt) rowp[nt * 16 + (l & 15)] = f2bf(acc[nt][b]);
    }
  }
  // fused attention scalars (waves 0-3 only)
  if (nhalf == 0) {
    const int lo = l & 15;
#pragma unroll
    for (int h = 0; h < 8; ++h) {
      const float a0 = as_[h * 32 + lo], a1 = as_[h * 32 + 16 + lo];
      const float d0 = ad_[h * 32 + lo], d1 = ad_[h * 32 + 16 + lo];
#pragma unroll
      for (int rb = 0; rb < 4; ++rb) {
        float ps = acc[2 * h][rb] * a0 + acc[2 * h + 1][rb] * a1;
        float pd = acc[2 * h][rb] * d0 + acc[2 * h + 1][rb] * d1;
#pragma unroll
        for (int off = 1; off <= 8; off <<= 1) {
          ps += __shfl_xor(ps, off);
          pd += __shfl_xor(pd, off);
        }
        if (lo == 0) {
          const int bn = base + (l >> 4) * 4 + rb;
          ssrc[(size_t)bn * NHEAD + h] = ps;
          sdst[(size_t)bn * NHEAD + h] = pd;
        }
      }
    }
  }
}

__global__ __launch_bounds__(1024) void k_scan(const int* __restrict__ cnt,
                                               int* __restrict__ off) {
  __shared__ int ls[1024];
  const int t = threadIdx.x;
  int own = 0;
  int deg[10];
  if (t < 1000) {
#pragma unroll
    for (int i = 0; i < 10; ++i) { deg[i] = cnt[t * 10 + i]; own += deg[i]; }
  }
  ls[t] = own;
  __syncthreads();
  for (int s = 1; s < 1024; s <<= 1) {
    int v = 0;
    if (t >= s) v = ls[t - s];
    __syncthreads();
    if (t >= s) ls[t] += v;
    __syncthreads();
  }
  if (t < 1000) {
    int start = ls[t] - own;
#pragma unroll
    for (int i = 0; i < 10; ++i) { off[t * 10 + i] = start; start += deg[i]; }
  }
  if (t == 0) off[NN] = EE;
}

__global__ void k_scatter(const int* __restrict__ ei, const int* __restrict__ off,
                          int* __restrict__ cur, int2* __restrict__ eidx,
                          int* __restrict__ inv) {
  int e = blockIdx.x * 256 + threadIdx.x;
  if (e >= EE) return;
  int s = ei[e], d = ei[EE + e];
  int pos = off[d] + atomicAdd(&cur[d], 1);
  eidx[pos] = make_int2(e, s);
  inv[e] = pos;
}

// ---- edge logits -> exp(logit) directly, CSR-order [pos][b][8].
__global__ __launch_bounds__(256) void k_elogit(
    const float* __restrict__ ea, const int* __restrict__ ei,
    const float* __restrict__ What, const float* __restrict__ ssrc,
    const float* __restrict__ sdst, const int* __restrict__ inv,
    float* __restrict__ exP) {
  __shared__ float sea[32 * 65];
  __shared__ float sw[64 * NHEAD];
  const int t = threadIdx.x;
  sw[t] = What[t];
  sw[t + 256] = What[t + 256];
  const int g0 = blockIdx.x * 32;
  const float* base = ea + (size_t)g0 * 64;
#pragma unroll
  for (int j = 0; j < 8; ++j) {
    int f = t + j * 256;
    sea[(f >> 6) * 65 + (f & 63)] = base[f];
  }
  __syncthreads();
  const int il = t >> 3, hh = t & 7;
  const int g = g0 + il;
  float acc = 0.f;
#pragma unroll
  for (int k = 0; k < 64; ++k) acc += sea[il * 65 + k] * sw[k * NHEAD + hh];
  const int b = g / EE, e = g - b * EE;
  const int src = ei[e], dst = ei[EE + e];
  float lg = ssrc[((size_t)b * NN + src) * NHEAD + hh] +
             sdst[((size_t)b * NN + dst) * NHEAD + hh] + acc;
  lg = lg > 0.f ? lg : 0.2f * lg;
  const int pos = inv[e];
  exP[(((size_t)pos * 4 + b) << 3) + hh] = __expf(lg);
}

// ---- aggregation + z@We16 + residual(overlay) + LN + ELU.
// DUAL-NODE: wave = (batch=wid), block = node pair (2*blk, 2*blk+1).
// Two independent gather chains per wave double memory-level parallelism.
#define AGG_BODY(i, u4, z0, z1, z2, z3, z4, z5, z6, z7, ss)                    \
  {                                                                            \
    const int2 es = eidx[i];                                                   \
    const float* exi = exb + ((size_t)(i) << 5);                               \
    const float4 xa = *reinterpret_cast<const float4*>(exi);                   \
    const float4 xb = *reinterpret_cast<const float4*>(exi + 4);               \
    const float exu = exi[hq];                                                 \
    ss += exi[hr];                                                             \
    const float eal = eab[(size_t)es.x * 64 + l];                              \
    const ushort4 h4 =                                                         \
        *reinterpret_cast<const ushort4*>(hb + ((size_t)es.y << 10) + 4 * l);  \
    z0 += xa.x * eal; z1 += xa.y * eal; z2 += xa.z * eal; z3 += xa.w * eal;    \
    z4 += xb.x * eal; z5 += xb.y * eal; z6 += xb.z * eal; z7 += xb.w * eal;    \
    u4.x += exu * bf2f(h4.x); u4.y += exu * bf2f(h4.y);                        \
    u4.z += exu * bf2f(h4.z); u4.w += exu * bf2f(h4.w);                        \
  }

__global__ __launch_bounds__(256) void k_agg(
    const float* __restrict__ ea, const unsigned short* __restrict__ h16,
    const float* __restrict__ exP, const int* __restrict__ off,
    const int2* __restrict__ eidx, const unsigned short* __restrict__ We16,
    const float* __restrict__ gam, const float* __restrict__ bet,
    float* __restrict__ out) {
  __shared__ float zshA[4][8 * 65];
  __shared__ float zshB[4][8 * 65];
  const int wid = threadIdx.x >> 6, l = threadIdx.x & 63;
  const int b = wid;
  const int nodeA = blockIdx.x * 2, nodeB = nodeA + 1;
  const int sA = off[nodeA], eAe = off[nodeA + 1], eBe = off[nodeB + 1];
  const int sB = eAe;  // CSR: segment B starts where A ends
  const int hq = l >> 3;
  const int hr = l & 7;
  float4 uA = {0.f, 0.f, 0.f, 0.f}, uB = {0.f, 0.f, 0.f, 0.f};
  float zA0 = 0.f, zA1 = 0.f, zA2 = 0.f, zA3 = 0.f;
  float zA4 = 0.f, zA5 = 0.f, zA6 = 0.f, zA7 = 0.f;
  float zB0 = 0.f, zB1 = 0.f, zB2 = 0.f, zB3 = 0.f;
  float zB4 = 0.f, zB5 = 0.f, zB6 = 0.f, zB7 = 0.f;
  float ssA = 0.f, ssB = 0.f;
  const float* __restrict__ exb = exP + ((size_t)b << 3);
  const float* __restrict__ eab = ea + (size_t)b * EE * 64;
  const unsigned short* __restrict__ hb = h16 + ((size_t)b << 8);
  const int nA = eAe - sA, nB = eBe - sB;
  const int nmin = nA < nB ? nA : nB;
  for (int j = 0; j < nmin; ++j) {
    AGG_BODY(sA + j, uA, zA0, zA1, zA2, zA3, zA4, zA5, zA6, zA7, ssA);
    AGG_BODY(sB + j, uB, zB0, zB1, zB2, zB3, zB4, zB5, zB6, zB7, ssB);
  }
  for (int j = nmin; j < nA; ++j)
    AGG_BODY(sA + j, uA, zA0, zA1, zA2, zA3, zA4, zA5, zA6, zA7, ssA);
  for (int j = nmin; j < nB; ++j)
    AGG_BODY(sB + j, uB, zB0, zB1, zB2, zB3, zB4, zB5, zB6, zB7, ssB);
  // publish partial z (wave-private LDS, no barrier needed)
  zshA[wid][0 * 65 + l] = zA0; zshA[wid][1 * 65 + l] = zA1;
  zshA[wid][2 * 65 + l] = zA2; zshA[wid][3 * 65 + l] = zA3;
  zshA[wid][4 * 65 + l] = zA4; zshA[wid][5 * 65 + l] = zA5;
  zshA[wid][6 * 65 + l] = zA6; zshA[wid][7 * 65 + l] = zA7;
  zshB[wid][0 * 65 + l] = zB0; zshB[wid][1 * 65 + l] = zB1;
  zshB[wid][2 * 65 + l] = zB2; zshB[wid][3 * 65 + l] = zB3;
  zshB[wid][4 * 65 + l] = zB4; zshB[wid][5 * 65 + l] = zB5;
  zshB[wid][6 * 65 + l] = zB6; zshB[wid][7 * 65 + l] = zB7;
  const size_t bnA = (size_t)b * NN + nodeA;
  const size_t bnB = bnA + 1;
  const unsigned short* __restrict__ ov =
      reinterpret_cast<const unsigned short*>(out);
  const ushort4 rA = *reinterpret_cast<const ushort4*>(ov + (bnA << 9) + 4 * l);
  const ushort4 rB = *reinterpret_cast<const ushort4*>(ov + (bnB << 9) + 4 * l);
  // z epilogue for both nodes; We16 row loaded once
#pragma unroll 8
  for (int k = 0; k < 64; ++k) {
    const float zkA = zshA[wid][hq * 65 + k];
    const float zkB = zshB[wid][hq * 65 + k];
    const ushort4 wv = *reinterpret_cast<const ushort4*>(We16 + (k << 8) + 4 * l);
    const float w0 = bf2f(wv.x), w1 = bf2f(wv.y), w2 = bf2f(wv.z), w3 = bf2f(wv.w);
    uA.x += zkA * w0; uA.y += zkA * w1; uA.z += zkA * w2; uA.w += zkA * w3;
    uB.x += zkB * w0; uB.y += zkB * w1; uB.z += zkB * w2; uB.w += zkB * w3;
  }
  const float sqA = __shfl(ssA, hq), sqB = __shfl(ssB, hq);
  const float scA = sqA > 0.f ? 1.f / sqA : 0.f;
  const float scB = sqB > 0.f ? 1.f / sqB : 0.f;
  uA.x = uA.x * scA + bf2f(rA.x); uA.y = uA.y * scA + bf2f(rA.y);
  uA.z = uA.z * scA + bf2f(rA.z); uA.w = uA.w * scA + bf2f(rA.w);
  uB.x = uB.x * scB + bf2f(rB.x); uB.y = uB.y * scB + bf2f(rB.y);
  uB.z = uB.z * scB + bf2f(rB.z); uB.w = uB.w * scB + bf2f(rB.w);
  // fused LayerNorm + ELU for both rows (interleaved shuffle reduces)
  float s1A = uA.x + uA.y + uA.z + uA.w;
  float s2A = uA.x * uA.x + uA.y * uA.y + uA.z * uA.z + uA.w * uA.w;
  float s1B = uB.x + uB.y + uB.z + uB.w;
  float s2B = uB.x * uB.x + uB.y * uB.y + uB.z * uB.z + uB.w * uB.w;
#pragma unroll
  for (int off2 = 1; off2 <= 32; off2 <<= 1) {
    s1A += __shfl_xor(s1A, off2);
    s2A += __shfl_xor(s2A, off2);
    s1B += __shfl_xor(s1B, off2);
    s2B += __shfl_xor(s2B, off2);
  }
  const float muA = s1A * (1.f / HID);
  const float varA = s2A * (1.f / HID) - muA * muA;
  const float rsA = rsqrtf(varA + 1e-5f);
  const float muB = s1B * (1.f / HID);
  const float varB = s2B * (1.f / HID) - muB * muB;
  const float rsB = rsqrtf(varB + 1e-5f);
  const float4 g4 = reinterpret_cast<const float4*>(gam)[l];
  const float4 b4 = reinterpret_cast<const float4*>(bet)[l];
  float4 yA, yB;
  yA.x = (uA.x - muA) * rsA * g4.x + b4.x;
  yA.y = (uA.y - muA) * rsA * g4.y + b4.y;
  yA.z = (uA.z - muA) * rsA * g4.z + b4.z;
  yA.w = (uA.w - muA) * rsA * g4.w + b4.w;
  yB.x = (uB.x - muB) * rsB * g4.x + b4.x;
  yB.y = (uB.y - muB) * rsB * g4.y + b4.y;
  yB.z = (uB.z - muB) * rsB * g4.z + b4.z;
  yB.w = (uB.w - muB) * rsB * g4.w + b4.w;
  yA.x = yA.x > 0.f ? yA.x : expm1f(yA.x);
  yA.y = yA.y > 0.f ? yA.y : expm1f(yA.y);
  yA.z = yA.z > 0.f ? yA.z : expm1f(yA.z);
  yA.w = yA.w > 0.f ? yA.w : expm1f(yA.w);
  yB.x = yB.x > 0.f ? yB.x : expm1f(yB.x);
  yB.y = yB.y > 0.f ? yB.y : expm1f(yB.y);
  yB.z = yB.z > 0.f ? yB.z : expm1f(yB.z);
  yB.w = yB.w > 0.f ? yB.w : expm1f(yB.w);
  *reinterpret_cast<float4*>(out + (bnA << 8) + 4 * l) = yA;
  *reinterpret_cast<float4*>(out + (bnB << 8) + 4 * l) = yB;
}

extern "C" void kernel_launch(void* const* d_in, const int* in_sizes, int n_in,
                              void* d_out, int out_size, void* d_ws, size_t ws_size,
                              hipStream_t stream) {
  const float* nf   = (const float*)d_in[0];
  const int*   ei   = (const int*)d_in[1];
  const float* eatt = (const float*)d_in[2];
  const float* Wn   = (const float*)d_in[3];
  const float* We   = (const float*)d_in[4];
  const float* Wr   = (const float*)d_in[5];
  const float* as_  = (const float*)d_in[6];
  const float* ad_  = (const float*)d_in[7];
  const float* ae_  = (const float*)d_in[8];
  const float* gam  = (const float*)d_in[9];
  const float* bet  = (const float*)d_in[10];
  float* out = (float*)d_out;

  // ---- workspace layout (~50 MB)
  char* ws = (char*)d_ws;
  size_t o = 0;
  auto alloc = [&](size_t bytes) -> void* {
    void* p = ws + o;
    o += (bytes + 255) & ~(size_t)255;
    return p;
  };
  unsigned short* h16  = (unsigned short*)alloc((size_t)BB * NN * HID * 2);
  float* ssrc   = (float*)alloc((size_t)BB * NN * NHEAD * 4);
  float* sdst   = (float*)alloc((size_t)BB * NN * NHEAD * 4);
  float* What   = (float*)alloc(64 * NHEAD * 4);
  unsigned short* We16 = (unsigned short*)alloc(64 * HID * 2);
  float* exP    = (float*)alloc((size_t)BB * EE * NHEAD * 4);
  int*  cnt     = (int*)alloc(NN * 4);
  int*  cur     = (int*)alloc(NN * 4);
  int*  offn    = (int*)alloc((NN + 1) * 4);
  int2* eidx    = (int2*)alloc((size_t)EE * 8);
  int*  inv     = (int*)alloc((size_t)EE * 4);
  unsigned short* Bpack = (unsigned short*)alloc((size_t)512 * 128 * 2);

  hipLaunchKernelGGL(k_prep, dim3(73), dim3(512), 0, stream,
                     We, ae_, Wn, Wr, What, We16, Bpack, cnt, cur);
  hipLaunchKernelGGL(k_projm, dim3(625 + (EE + 511) / 512), dim3(512), 0, stream,
                     nf, Bpack, as_, ad_, h16, out, ssrc, sdst, ei, cnt);
  hipLaunchKernelGGL(k_scan, dim3(1), dim3(1024), 0, stream, cnt, offn);
  hipLaunchKernelGGL(k_scatter, dim3((EE + 255) / 256), dim3(256), 0, stream,
                     ei, offn, cur, eidx, inv);
  hipLaunchKernelGGL(k_elogit, dim3(BB * EE / 32), dim3(256), 0, stream,
                     eatt, ei, What, ssrc, sdst, inv, exP);
  hipLaunchKernelGGL(k_agg, dim3(NN / 2), dim3(256), 0, stream,
                     eatt, h16, exP, offn, eidx, We16, gam, bet, out);
}